// Round 1
// baseline (923.774 us; speedup 1.0000x reference)
//
#include <hip/hip_runtime.h>

#define D_IN 256
#define D_OUT 128
#define BM 64
#define BK 64

// ---------------- GEMM: h[M,128] = x[M,256] @ W[256,128], fp32 ----------------
__global__ __launch_bounds__(256) void gemm_kernel(const float* __restrict__ x,
                                                   const float* __restrict__ W,
                                                   float* __restrict__ h, int M) {
    __shared__ float sX[BM][BK];      // [row][k]
    __shared__ float sW[BK][D_OUT];   // [k][col]
    const int tid = threadIdx.x;
    const int m0  = blockIdx.x * BM;
    const int c4  = (tid & 31) * 4;   // column base (0..124)
    const int r8  = (tid >> 5) * 8;   // row base (0..56)

    float4 acc[8];
#pragma unroll
    for (int r = 0; r < 8; ++r) acc[r] = make_float4(0.f, 0.f, 0.f, 0.f);

    for (int kt = 0; kt < D_IN; kt += BK) {
        // stage x tile: 64 rows x 64 k = 1024 float4
#pragma unroll
        for (int i = 0; i < 4; ++i) {
            int idx = tid + i * 256;
            int rl = idx >> 4;
            int k4 = (idx & 15) * 4;
            int row = m0 + rl;
            float4 v = make_float4(0.f, 0.f, 0.f, 0.f);
            if (row < M) v = *(const float4*)&x[(size_t)row * D_IN + kt + k4];
            *(float4*)&sX[rl][k4] = v;
        }
        // stage W tile: 64 k x 128 cols = 2048 float4
#pragma unroll
        for (int i = 0; i < 8; ++i) {
            int idx = tid + i * 256;
            int kl = idx >> 5;
            int c  = (idx & 31) * 4;
            *(float4*)&sW[kl][c] = *(const float4*)&W[(size_t)(kt + kl) * D_OUT + c];
        }
        __syncthreads();

#pragma unroll 8
        for (int kk = 0; kk < BK; ++kk) {
            float4 w4 = *(const float4*)&sW[kk][c4];
#pragma unroll
            for (int r = 0; r < 8; ++r) {
                float xv = sX[r8 + r][kk];
                acc[r].x += xv * w4.x;
                acc[r].y += xv * w4.y;
                acc[r].z += xv * w4.z;
                acc[r].w += xv * w4.w;
            }
        }
        __syncthreads();
    }
#pragma unroll
    for (int r = 0; r < 8; ++r) {
        int row = m0 + r8 + r;
        if (row < M) *(float4*)&h[(size_t)row * D_OUT + c4] = acc[r];
    }
}

// ---------------- CSR build ----------------
__global__ void hist_kernel(const int* __restrict__ dst, int* __restrict__ count, int E) {
    int i = blockIdx.x * blockDim.x + threadIdx.x;
    int stride = gridDim.x * blockDim.x;
    for (; i < E; i += stride) atomicAdd(&count[dst[i]], 1);
}

__global__ void scan1_kernel(const int* __restrict__ count, int* __restrict__ offsets,
                             int* __restrict__ bsum, int N) {
    __shared__ int s[256];
    int tid = threadIdx.x;
    int i = blockIdx.x * 256 + tid;
    int v = (i < N) ? count[i] : 0;
    s[tid] = v;
    __syncthreads();
    for (int off = 1; off < 256; off <<= 1) {
        int t = (tid >= off) ? s[tid - off] : 0;
        __syncthreads();
        s[tid] += t;
        __syncthreads();
    }
    if (i < N) offsets[i] = s[tid] - v;          // exclusive within block
    if (tid == 255) bsum[blockIdx.x] = s[255];   // block total
}

__global__ void scan2_kernel(const int* __restrict__ bsum, int* __restrict__ bscan, int NB) {
    __shared__ int s[512];
    int tid = threadIdx.x;
    int v = (tid < NB) ? bsum[tid] : 0;
    s[tid] = v;
    __syncthreads();
    for (int off = 1; off < 512; off <<= 1) {
        int t = (tid >= off) ? s[tid - off] : 0;
        __syncthreads();
        s[tid] += t;
        __syncthreads();
    }
    if (tid < NB) bscan[tid] = s[tid] - v;       // exclusive across blocks
}

__global__ void scan3_kernel(int* __restrict__ offsets, const int* __restrict__ bscan,
                             int* __restrict__ cursor, int N) {
    int i = blockIdx.x * blockDim.x + threadIdx.x;
    if (i < N) {
        int o = offsets[i] + bscan[i >> 8];
        offsets[i] = o;
        cursor[i]  = o;
    }
}

__global__ void scatter_kernel(const int* __restrict__ src, const int* __restrict__ dst,
                               const float* __restrict__ w, int* __restrict__ cursor,
                               int* __restrict__ ssrc, float* __restrict__ sw, int E) {
    int i = blockIdx.x * blockDim.x + threadIdx.x;
    int stride = gridDim.x * blockDim.x;
    for (; i < E; i += stride) {
        int d = dst[i];
        int pos = atomicAdd(&cursor[d], 1);
        ssrc[pos] = src[i];
        sw[pos]   = w[i];
    }
}

// ---------------- SpMM: one wave per destination node ----------------
__global__ __launch_bounds__(256) void spmm_kernel(const int* __restrict__ offsets,
                                                   const int* __restrict__ count,
                                                   const int* __restrict__ ssrc,
                                                   const float* __restrict__ sw,
                                                   const float* __restrict__ h,
                                                   float* __restrict__ out, int N) {
    int wid  = (blockIdx.x * 256 + threadIdx.x) >> 6;   // node id
    int lane = threadIdx.x & 63;
    if (wid >= N) return;
    int start = offsets[wid];
    int cnt   = count[wid];
    float2 acc = make_float2(0.f, 0.f);
    for (int j = 0; j < cnt; ++j) {
        int e = start + j;
        int s = ssrc[e];
        float ww = sw[e];
        const float2 hv = *(const float2*)&h[(size_t)s * D_OUT + lane * 2];
        acc.x += ww * hv.x;
        acc.y += ww * hv.y;
    }
    *(float2*)&out[(size_t)wid * D_OUT + lane * 2] = acc;
}

// ---------------- fallback: atomic scatter (if ws too small for CSR) ----------------
__global__ __launch_bounds__(256) void edge_atomic_kernel(const int* __restrict__ src,
                                                          const int* __restrict__ dst,
                                                          const float* __restrict__ w,
                                                          const float* __restrict__ h,
                                                          float* __restrict__ out, int E) {
    int wid  = (blockIdx.x * 256 + threadIdx.x) >> 6;
    int lane = threadIdx.x & 63;
    if (wid >= E) return;
    int s = src[wid], d = dst[wid];
    float ww = w[wid];
    const float2 hv = *(const float2*)&h[(size_t)s * D_OUT + lane * 2];
    atomicAdd(&out[(size_t)d * D_OUT + lane * 2 + 0], ww * hv.x);
    atomicAdd(&out[(size_t)d * D_OUT + lane * 2 + 1], ww * hv.y);
}

extern "C" void kernel_launch(void* const* d_in, const int* in_sizes, int n_in,
                              void* d_out, int out_size, void* d_ws, size_t ws_size,
                              hipStream_t stream) {
    const float* x    = (const float*)d_in[0];
    const float* W    = (const float*)d_in[1];
    const int*   esrc = (const int*)d_in[2];
    const int*   edst = (const int*)d_in[3];
    const float* ew   = (const float*)d_in[4];
    float* out = (float*)d_out;

    const int M = in_sizes[0] / D_IN;   // 100000 nodes
    const int E = in_sizes[2];          // 3200000 edges

    char* ws = (char*)d_ws;
    size_t off = 0;
    float* h       = (float*)(ws + off); off += (size_t)M * D_OUT * 4;
    int*   ssrc    = (int*)  (ws + off); off += (size_t)E * 4;
    float* sw      = (float*)(ws + off); off += (size_t)E * 4;
    int*   offsets = (int*)  (ws + off); off += (size_t)M * 4;
    int*   count   = (int*)  (ws + off); off += (size_t)M * 4;
    int*   cursor  = (int*)  (ws + off); off += (size_t)M * 4;
    int*   bsum    = (int*)  (ws + off); off += 2048;
    int*   bscan   = (int*)  (ws + off); off += 2048;
    const bool use_csr = (off <= ws_size);

    // dense projection
    gemm_kernel<<<(M + BM - 1) / BM, 256, 0, stream>>>(x, W, h, M);

    if (use_csr) {
        int NB = (M + 255) / 256;   // 391 blocks; scan2 handles up to 512
        hipMemsetAsync(count, 0, (size_t)M * 4, stream);
        hist_kernel  <<<2048, 256, 0, stream>>>(edst, count, E);
        scan1_kernel <<<NB, 256, 0, stream>>>(count, offsets, bsum, M);
        scan2_kernel <<<1, 512, 0, stream>>>(bsum, bscan, NB);
        scan3_kernel <<<NB, 256, 0, stream>>>(offsets, bscan, cursor, M);
        scatter_kernel<<<2048, 256, 0, stream>>>(esrc, edst, ew, cursor, ssrc, sw, E);
        spmm_kernel  <<<(M + 3) / 4, 256, 0, stream>>>(offsets, count, ssrc, sw, h, out, M);
    } else {
        hipMemsetAsync(d_out, 0, (size_t)out_size * 4, stream);
        long long nthreads = (long long)E * 64;
        edge_atomic_kernel<<<(nthreads + 255) / 256, 256, 0, stream>>>(esrc, edst, ew, h, out, E);
    }
}

// Round 2
// 728.376 us; speedup vs baseline: 1.2683x; 1.2683x over previous
//
#include <hip/hip_runtime.h>

#define D_IN 256
#define D_OUT 128

typedef __bf16  bf16x8 __attribute__((ext_vector_type(8)));
typedef float   f32x4  __attribute__((ext_vector_type(4)));

// ---------------- W transpose + bf16: Wt[col][k] = bf16(W[k][col]) ----------------
__global__ __launch_bounds__(256) void wtrans_kernel(const float* __restrict__ W,
                                                     __bf16* __restrict__ Wt) {
    int n = blockIdx.x * 256 + threadIdx.x;       // 32768 elems
    int k = n >> 7;            // 0..255
    int col = n & 127;         // 0..127
    Wt[(size_t)col * D_IN + k] = (__bf16)W[(size_t)k * D_OUT + col];
}

// ---------------- GEMM: h16[M,128] = bf16( x[M,256] @ W[256,128] ) via MFMA ----------------
// block: 256 thr = 4 waves; each wave: 32 rows x 128 cols; block: 128 rows.
__global__ __launch_bounds__(256) void gemm_mfma_kernel(const float* __restrict__ x,
                                                        const __bf16* __restrict__ Wt,
                                                        __bf16* __restrict__ h16, int M) {
    const int lane = threadIdx.x & 63;
    const int wid  = threadIdx.x >> 6;
    const int r0   = blockIdx.x * 128 + wid * 32;
    const int lr   = lane & 15;          // row-in-tile for A, col-in-tile for B
    const int koff = (lane >> 4) * 8;    // k offset within 32-k tile

    int rowA = r0 + lr;        if (rowA >= M) rowA = M - 1;
    int rowB = r0 + 16 + lr;   if (rowB >= M) rowB = M - 1;
    const float* pa0 = &x[(size_t)rowA * D_IN + koff];
    const float* pa1 = &x[(size_t)rowB * D_IN + koff];

    f32x4 acc0[8], acc1[8];
#pragma unroll
    for (int c = 0; c < 8; ++c) { acc0[c] = (f32x4)0.f; acc1[c] = (f32x4)0.f; }

#pragma unroll
    for (int t = 0; t < 8; ++t) {
        float4 fa0 = *(const float4*)(pa0 + t * 32);
        float4 fa1 = *(const float4*)(pa0 + t * 32 + 4);
        float4 fb0 = *(const float4*)(pa1 + t * 32);
        float4 fb1 = *(const float4*)(pa1 + t * 32 + 4);
        bf16x8 aA, aB;
        aA[0]=(__bf16)fa0.x; aA[1]=(__bf16)fa0.y; aA[2]=(__bf16)fa0.z; aA[3]=(__bf16)fa0.w;
        aA[4]=(__bf16)fa1.x; aA[5]=(__bf16)fa1.y; aA[6]=(__bf16)fa1.z; aA[7]=(__bf16)fa1.w;
        aB[0]=(__bf16)fb0.x; aB[1]=(__bf16)fb0.y; aB[2]=(__bf16)fb0.z; aB[3]=(__bf16)fb0.w;
        aB[4]=(__bf16)fb1.x; aB[5]=(__bf16)fb1.y; aB[6]=(__bf16)fb1.z; aB[7]=(__bf16)fb1.w;
#pragma unroll
        for (int c = 0; c < 8; ++c) {
            bf16x8 b = *(const bf16x8*)&Wt[(size_t)(c * 16 + lr) * D_IN + t * 32 + koff];
            acc0[c] = __builtin_amdgcn_mfma_f32_16x16x32_bf16(aA, b, acc0[c], 0, 0, 0);
            acc1[c] = __builtin_amdgcn_mfma_f32_16x16x32_bf16(aB, b, acc1[c], 0, 0, 0);
        }
    }

    // D layout: col = lane&15, row = (lane>>4)*4 + i
    const int q = lane >> 4;
#pragma unroll
    for (int c = 0; c < 8; ++c) {
        int col = c * 16 + lr;
#pragma unroll
        for (int i = 0; i < 4; ++i) {
            int ra = r0 + q * 4 + i;
            int rb = r0 + 16 + q * 4 + i;
            if (ra < M) h16[(size_t)ra * D_OUT + col] = (__bf16)acc0[c][i];
            if (rb < M) h16[(size_t)rb * D_OUT + col] = (__bf16)acc1[c][i];
        }
    }
}

// ---------------- CSR build ----------------
__global__ void hist_kernel(const int* __restrict__ dst, int* __restrict__ count, int E) {
    int i = blockIdx.x * blockDim.x + threadIdx.x;
    int stride = gridDim.x * blockDim.x;
    for (; i < E; i += stride) atomicAdd(&count[dst[i]], 1);
}

__global__ void scan1_kernel(const int* __restrict__ count, int* __restrict__ offsets,
                             int* __restrict__ bsum, int N) {
    __shared__ int s[256];
    int tid = threadIdx.x;
    int i = blockIdx.x * 256 + tid;
    int v = (i < N) ? count[i] : 0;
    s[tid] = v;
    __syncthreads();
    for (int off = 1; off < 256; off <<= 1) {
        int t = (tid >= off) ? s[tid - off] : 0;
        __syncthreads();
        s[tid] += t;
        __syncthreads();
    }
    if (i < N) offsets[i] = s[tid] - v;
    if (tid == 255) bsum[blockIdx.x] = s[255];
}

__global__ void scan2_kernel(const int* __restrict__ bsum, int* __restrict__ bscan, int NB) {
    __shared__ int s[512];
    int tid = threadIdx.x;
    int v = (tid < NB) ? bsum[tid] : 0;
    s[tid] = v;
    __syncthreads();
    for (int off = 1; off < 512; off <<= 1) {
        int t = (tid >= off) ? s[tid - off] : 0;
        __syncthreads();
        s[tid] += t;
        __syncthreads();
    }
    if (tid < NB) bscan[tid] = s[tid] - v;
}

__global__ void scan3_kernel(int* __restrict__ offsets, const int* __restrict__ bscan,
                             int* __restrict__ cursor, int N) {
    int i = blockIdx.x * blockDim.x + threadIdx.x;
    if (i < N) {
        int o = offsets[i] + bscan[i >> 8];
        offsets[i] = o;
        cursor[i]  = o;
    }
}

__global__ void scatter_kernel(const int* __restrict__ src, const int* __restrict__ dst,
                               const float* __restrict__ w, int* __restrict__ cursor,
                               int2* __restrict__ ep, int E) {
    int i = blockIdx.x * blockDim.x + threadIdx.x;
    int stride = gridDim.x * blockDim.x;
    for (; i < E; i += stride) {
        int d = dst[i];
        int pos = atomicAdd(&cursor[d], 1);
        ep[pos] = make_int2(src[i], __float_as_int(w[i]));
    }
}

// ---------------- SpMM: one wave per destination node, 8-deep MLP ----------------
__global__ __launch_bounds__(256) void spmm_kernel(const int* __restrict__ offsets,
                                                   const int* __restrict__ count,
                                                   const int2* __restrict__ ep,
                                                   const unsigned int* __restrict__ h16,
                                                   float* __restrict__ out, int N) {
    int wid  = (blockIdx.x * 256 + threadIdx.x) >> 6;   // node id
    int lane = threadIdx.x & 63;
    if (wid >= N) return;
    int start = offsets[wid];
    int cnt   = count[wid];
    float ax = 0.f, ay = 0.f;
    for (int j = 0; j < cnt; j += 8) {
        int2 e[8]; float wt[8];
#pragma unroll
        for (int k = 0; k < 8; ++k) {
            int jj = j + k;
            int idx = start + (jj < cnt ? jj : cnt - 1);
            e[k] = ep[idx];
            wt[k] = (jj < cnt) ? __int_as_float(e[k].y) : 0.f;
        }
        unsigned int u[8];
#pragma unroll
        for (int k = 0; k < 8; ++k)
            u[k] = h16[(size_t)e[k].x * 64 + lane];
#pragma unroll
        for (int k = 0; k < 8; ++k) {
            float flo = __uint_as_float(u[k] << 16);
            float fhi = __uint_as_float(u[k] & 0xffff0000u);
            ax += wt[k] * flo;
            ay += wt[k] * fhi;
        }
    }
    out[(size_t)wid * D_OUT + lane * 2 + 0] = ax;
    out[(size_t)wid * D_OUT + lane * 2 + 1] = ay;
}

// ---------------- fallback: atomic scatter (if ws too small for CSR) ----------------
__global__ __launch_bounds__(256) void edge_atomic_kernel(const int* __restrict__ src,
                                                          const int* __restrict__ dst,
                                                          const float* __restrict__ w,
                                                          const unsigned int* __restrict__ h16,
                                                          float* __restrict__ out, int E) {
    int wid  = (blockIdx.x * 256 + threadIdx.x) >> 6;
    int lane = threadIdx.x & 63;
    if (wid >= E) return;
    int s = src[wid], d = dst[wid];
    float ww = w[wid];
    unsigned int u = h16[(size_t)s * 64 + lane];
    atomicAdd(&out[(size_t)d * D_OUT + lane * 2 + 0], ww * __uint_as_float(u << 16));
    atomicAdd(&out[(size_t)d * D_OUT + lane * 2 + 1], ww * __uint_as_float(u & 0xffff0000u));
}

extern "C" void kernel_launch(void* const* d_in, const int* in_sizes, int n_in,
                              void* d_out, int out_size, void* d_ws, size_t ws_size,
                              hipStream_t stream) {
    const float* x    = (const float*)d_in[0];
    const float* W    = (const float*)d_in[1];
    const int*   esrc = (const int*)d_in[2];
    const int*   edst = (const int*)d_in[3];
    const float* ew   = (const float*)d_in[4];
    float* out = (float*)d_out;

    const int M = in_sizes[0] / D_IN;   // 100000 nodes
    const int E = in_sizes[2];          // 3200000 edges

    char* ws = (char*)d_ws;
    size_t off = 0;
    __bf16* h16    = (__bf16*)(ws + off); off += (size_t)M * D_OUT * 2;  // 25.6 MB
    int2*   ep     = (int2*)  (ws + off); off += (size_t)E * 8;          // 25.6 MB
    __bf16* Wt     = (__bf16*)(ws + off); off += (size_t)D_IN * D_OUT * 2;
    int*    offsets= (int*)   (ws + off); off += (size_t)M * 4;
    int*    count  = (int*)   (ws + off); off += (size_t)M * 4;
    int*    cursor = (int*)   (ws + off); off += (size_t)M * 4;
    int*    bsum   = (int*)   (ws + off); off += 2048;
    int*    bscan  = (int*)   (ws + off); off += 2048;
    const bool use_csr = (off <= ws_size);

    // dense projection (bf16 MFMA)
    wtrans_kernel<<<(D_IN * D_OUT + 255) / 256, 256, 0, stream>>>(W, Wt);
    gemm_mfma_kernel<<<(M + 127) / 128, 256, 0, stream>>>(x, Wt, h16, M);

    if (use_csr) {
        int NB = (M + 255) / 256;   // 391 blocks; scan2 handles up to 512
        hipMemsetAsync(count, 0, (size_t)M * 4, stream);
        hist_kernel  <<<2048, 256, 0, stream>>>(edst, count, E);
        scan1_kernel <<<NB, 256, 0, stream>>>(count, offsets, bsum, M);
        scan2_kernel <<<1, 512, 0, stream>>>(bsum, bscan, NB);
        scan3_kernel <<<NB, 256, 0, stream>>>(offsets, bscan, cursor, M);
        scatter_kernel<<<2048, 256, 0, stream>>>(esrc, edst, ew, cursor, ep, E);
        spmm_kernel  <<<(M + 3) / 4, 256, 0, stream>>>(offsets, count, ep,
                                                       (const unsigned int*)h16, out, M);
    } else {
        hipMemsetAsync(d_out, 0, (size_t)out_size * 4, stream);
        long long nthreads = (long long)E * 64;
        edge_atomic_kernel<<<(nthreads + 255) / 256, 256, 0, stream>>>(
            esrc, edst, ew, (const unsigned int*)h16, out, E);
    }
}

// Round 3
// 602.723 us; speedup vs baseline: 1.5327x; 1.2085x over previous
//
#include <hip/hip_runtime.h>

#define D_IN 256
#define D_OUT 128

typedef __bf16  bf16x8 __attribute__((ext_vector_type(8)));
typedef float   f32x4  __attribute__((ext_vector_type(4)));

// ---------------- W transpose + bf16: Wt[col][k] = bf16(W[k][col]) ----------------
__global__ __launch_bounds__(256) void wtrans_kernel(const float* __restrict__ W,
                                                     __bf16* __restrict__ Wt) {
    int n = blockIdx.x * 256 + threadIdx.x;       // 32768 elems
    int k = n >> 7;            // 0..255
    int col = n & 127;         // 0..127
    Wt[(size_t)col * D_IN + k] = (__bf16)W[(size_t)k * D_OUT + col];
}

// ---------------- GEMM: h16[M,128] = bf16( x[M,256] @ W[256,128] ) via MFMA ----------------
__global__ __launch_bounds__(256) void gemm_mfma_kernel(const float* __restrict__ x,
                                                        const __bf16* __restrict__ Wt,
                                                        __bf16* __restrict__ h16, int M) {
    const int lane = threadIdx.x & 63;
    const int wid  = threadIdx.x >> 6;
    const int r0   = blockIdx.x * 128 + wid * 32;
    const int lr   = lane & 15;          // row-in-tile for A, col-in-tile for B
    const int koff = (lane >> 4) * 8;    // k offset within 32-k tile

    int rowA = r0 + lr;        if (rowA >= M) rowA = M - 1;
    int rowB = r0 + 16 + lr;   if (rowB >= M) rowB = M - 1;
    const float* pa0 = &x[(size_t)rowA * D_IN + koff];
    const float* pa1 = &x[(size_t)rowB * D_IN + koff];

    f32x4 acc0[8], acc1[8];
#pragma unroll
    for (int c = 0; c < 8; ++c) { acc0[c] = (f32x4)0.f; acc1[c] = (f32x4)0.f; }

#pragma unroll
    for (int t = 0; t < 8; ++t) {
        float4 fa0 = *(const float4*)(pa0 + t * 32);
        float4 fa1 = *(const float4*)(pa0 + t * 32 + 4);
        float4 fb0 = *(const float4*)(pa1 + t * 32);
        float4 fb1 = *(const float4*)(pa1 + t * 32 + 4);
        bf16x8 aA, aB;
        aA[0]=(__bf16)fa0.x; aA[1]=(__bf16)fa0.y; aA[2]=(__bf16)fa0.z; aA[3]=(__bf16)fa0.w;
        aA[4]=(__bf16)fa1.x; aA[5]=(__bf16)fa1.y; aA[6]=(__bf16)fa1.z; aA[7]=(__bf16)fa1.w;
        aB[0]=(__bf16)fb0.x; aB[1]=(__bf16)fb0.y; aB[2]=(__bf16)fb0.z; aB[3]=(__bf16)fb0.w;
        aB[4]=(__bf16)fb1.x; aB[5]=(__bf16)fb1.y; aB[6]=(__bf16)fb1.z; aB[7]=(__bf16)fb1.w;
#pragma unroll
        for (int c = 0; c < 8; ++c) {
            bf16x8 b = *(const bf16x8*)&Wt[(size_t)(c * 16 + lr) * D_IN + t * 32 + koff];
            acc0[c] = __builtin_amdgcn_mfma_f32_16x16x32_bf16(aA, b, acc0[c], 0, 0, 0);
            acc1[c] = __builtin_amdgcn_mfma_f32_16x16x32_bf16(aB, b, acc1[c], 0, 0, 0);
        }
    }

    const int q = lane >> 4;
#pragma unroll
    for (int c = 0; c < 8; ++c) {
        int col = c * 16 + lr;
#pragma unroll
        for (int i = 0; i < 4; ++i) {
            int ra = r0 + q * 4 + i;
            int rb = r0 + 16 + q * 4 + i;
            if (ra < M) h16[(size_t)ra * D_OUT + col] = (__bf16)acc0[c][i];
            if (rb < M) h16[(size_t)rb * D_OUT + col] = (__bf16)acc1[c][i];
        }
    }
}

// ---------------- hist + per-edge rank ----------------
__global__ void hist_kernel(const int* __restrict__ dst, int* __restrict__ count,
                            int* __restrict__ rank, int E) {
    int i = blockIdx.x * blockDim.x + threadIdx.x;
    int stride = gridDim.x * blockDim.x;
    for (; i < E; i += stride) rank[i] = atomicAdd(&count[dst[i]], 1);
}

__global__ void scan1_kernel(const int* __restrict__ count, int* __restrict__ offsets,
                             int* __restrict__ bsum, int N) {
    __shared__ int s[256];
    int tid = threadIdx.x;
    int i = blockIdx.x * 256 + tid;
    int v = (i < N) ? count[i] : 0;
    s[tid] = v;
    __syncthreads();
    for (int off = 1; off < 256; off <<= 1) {
        int t = (tid >= off) ? s[tid - off] : 0;
        __syncthreads();
        s[tid] += t;
        __syncthreads();
    }
    if (i < N) offsets[i] = s[tid] - v;
    if (tid == 255) bsum[blockIdx.x] = s[255];
}

__global__ void scan2_kernel(const int* __restrict__ bsum, int* __restrict__ bscan, int NB) {
    __shared__ int s[512];
    int tid = threadIdx.x;
    int v = (tid < NB) ? bsum[tid] : 0;
    s[tid] = v;
    __syncthreads();
    for (int off = 1; off < 512; off <<= 1) {
        int t = (tid >= off) ? s[tid - off] : 0;
        __syncthreads();
        s[tid] += t;
        __syncthreads();
    }
    if (tid < NB) bscan[tid] = s[tid] - v;
}

__global__ void scan3_kernel(int* __restrict__ offsets, const int* __restrict__ bscan, int N) {
    int i = blockIdx.x * blockDim.x + threadIdx.x;
    if (i < N) offsets[i] += bscan[i >> 8];
}

// ---------------- scatter: XCD-partitioned, atomic-free ----------------
// grid = NCHUNK*8; blockIdx&7 selects a dst-node range so each XCD's L2 owns
// a private slice of ep -> full-line write combining (kills the 8x write amp).
__global__ __launch_bounds__(256) void scatter_kernel(const int* __restrict__ src,
                                                      const int* __restrict__ dst,
                                                      const float* __restrict__ w,
                                                      const int* __restrict__ rank,
                                                      const int* __restrict__ offsets,
                                                      int2* __restrict__ ep,
                                                      int E, int npx, int CS) {
    const int xcd   = blockIdx.x & 7;
    const int chunk = blockIdx.x >> 3;
    const int lo = xcd * npx;
    const int hi = lo + npx;
    const int e1 = min(E, (chunk + 1) * CS);
    for (int i = chunk * CS + threadIdx.x; i < e1; i += 256) {
        int d = dst[i];
        if (d >= lo && d < hi) {
            int pos = offsets[d] + rank[i];
            ep[pos] = make_int2(src[i], __float_as_int(w[i]));
        }
    }
}

// ---------------- SpMM: one wave per destination node, 16-deep MLP ----------------
__global__ __launch_bounds__(256) void spmm_kernel(const int* __restrict__ offsets,
                                                   const int* __restrict__ count,
                                                   const int2* __restrict__ ep,
                                                   const unsigned int* __restrict__ h16,
                                                   float* __restrict__ out, int N) {
    int wid  = (blockIdx.x * 256 + threadIdx.x) >> 6;   // node id
    int lane = threadIdx.x & 63;
    if (wid >= N) return;
    int start = offsets[wid];
    int cnt   = count[wid];
    float ax = 0.f, ay = 0.f;
    for (int j = 0; j < cnt; j += 16) {
        int2 e[16]; float wt[16];
#pragma unroll
        for (int k = 0; k < 16; ++k) {
            int jj = j + k;
            int idx = start + (jj < cnt ? jj : cnt - 1);
            e[k] = ep[idx];
            wt[k] = (jj < cnt) ? __int_as_float(e[k].y) : 0.f;
        }
        unsigned int u[16];
#pragma unroll
        for (int k = 0; k < 16; ++k)
            u[k] = h16[(size_t)e[k].x * 64 + lane];
#pragma unroll
        for (int k = 0; k < 16; ++k) {
            ax += wt[k] * __uint_as_float(u[k] << 16);
            ay += wt[k] * __uint_as_float(u[k] & 0xffff0000u);
        }
    }
    out[(size_t)wid * D_OUT + lane * 2 + 0] = ax;
    out[(size_t)wid * D_OUT + lane * 2 + 1] = ay;
}

// ---------------- fallback: atomic scatter (if ws too small for CSR) ----------------
__global__ __launch_bounds__(256) void edge_atomic_kernel(const int* __restrict__ src,
                                                          const int* __restrict__ dst,
                                                          const float* __restrict__ w,
                                                          const unsigned int* __restrict__ h16,
                                                          float* __restrict__ out, int E) {
    int wid  = (blockIdx.x * 256 + threadIdx.x) >> 6;
    int lane = threadIdx.x & 63;
    if (wid >= E) return;
    int s = src[wid], d = dst[wid];
    float ww = w[wid];
    unsigned int u = h16[(size_t)s * 64 + lane];
    atomicAdd(&out[(size_t)d * D_OUT + lane * 2 + 0], ww * __uint_as_float(u << 16));
    atomicAdd(&out[(size_t)d * D_OUT + lane * 2 + 1], ww * __uint_as_float(u & 0xffff0000u));
}

extern "C" void kernel_launch(void* const* d_in, const int* in_sizes, int n_in,
                              void* d_out, int out_size, void* d_ws, size_t ws_size,
                              hipStream_t stream) {
    const float* x    = (const float*)d_in[0];
    const float* W    = (const float*)d_in[1];
    const int*   esrc = (const int*)d_in[2];
    const int*   edst = (const int*)d_in[3];
    const float* ew   = (const float*)d_in[4];
    float* out = (float*)d_out;

    const int M = in_sizes[0] / D_IN;   // 100000 nodes
    const int E = in_sizes[2];          // 3200000 edges

    char* ws = (char*)d_ws;
    size_t off = 0;
    __bf16* h16    = (__bf16*)(ws + off); off += (size_t)M * D_OUT * 2;  // 25.6 MB
    int2*   ep     = (int2*)  (ws + off); off += (size_t)E * 8;          // 25.6 MB
    int*    rank   = (int*)   (ws + off); off += (size_t)E * 4;          // 12.8 MB
    __bf16* Wt     = (__bf16*)(ws + off); off += (size_t)D_IN * D_OUT * 2;
    int*    offsets= (int*)   (ws + off); off += (size_t)M * 4;
    int*    count  = (int*)   (ws + off); off += (size_t)M * 4;
    int*    bsum   = (int*)   (ws + off); off += 2048;
    int*    bscan  = (int*)   (ws + off); off += 2048;
    const bool use_csr = (off <= ws_size);

    // dense projection (bf16 MFMA)
    wtrans_kernel<<<(D_IN * D_OUT + 255) / 256, 256, 0, stream>>>(W, Wt);
    gemm_mfma_kernel<<<(M + 127) / 128, 256, 0, stream>>>(x, Wt, h16, M);

    if (use_csr) {
        int NB = (M + 255) / 256;   // 391 blocks; scan2 handles up to 512
        hipMemsetAsync(count, 0, (size_t)M * 4, stream);
        hist_kernel  <<<2048, 256, 0, stream>>>(edst, count, rank, E);
        scan1_kernel <<<NB, 256, 0, stream>>>(count, offsets, bsum, M);
        scan2_kernel <<<1, 512, 0, stream>>>(bsum, bscan, NB);
        scan3_kernel <<<NB, 256, 0, stream>>>(offsets, bscan, M);

        const int NCHUNK = 256;
        const int CS  = (E + NCHUNK - 1) / NCHUNK;   // edges per chunk
        const int npx = (M + 7) / 8;                 // nodes per XCD range
        scatter_kernel<<<NCHUNK * 8, 256, 0, stream>>>(esrc, edst, ew, rank, offsets,
                                                       ep, E, npx, CS);
        spmm_kernel  <<<(M + 3) / 4, 256, 0, stream>>>(offsets, count, ep,
                                                       (const unsigned int*)h16, out, M);
    } else {
        hipMemsetAsync(d_out, 0, (size_t)out_size * 4, stream);
        long long nthreads = (long long)E * 64;
        edge_atomic_kernel<<<(nthreads + 255) / 256, 256, 0, stream>>>(
            esrc, edst, ew, (const unsigned int*)h16, out, E);
    }
}